// Round 4
// baseline (901.823 us; speedup 1.0000x reference)
//
#include <hip/hip_runtime.h>
#include <hip/hip_bf16.h>
#include <cstdint>
#include <cstddef>

typedef __hip_bfloat16 bf16;
typedef __bf16 bf16x8 __attribute__((ext_vector_type(8)));
typedef float f32x4 __attribute__((ext_vector_type(4)));

#define S_D 30
#define C_D 16
#define N_R 46        // S_D + C_D rows per batch
#define H_D 768
#define NW  4608      // wide-proj cols: [Ws|Wr0|Wr1|Wr2|Wr3|Wg_x]
#define EPS_F 1e-5f

// ------------------------------------------------------------------
// prep: normalize adjacency matrices once (they are layer-invariant)
// ------------------------------------------------------------------
__global__ __launch_bounds__(64) void prep_norm_k(
    const float* __restrict__ a_cur, const float* __restrict__ a_slot,
    const float* __restrict__ a_last, const float* __restrict__ a_dom,
    float* __restrict__ Acr, float* __restrict__ Acc, float* __restrict__ Asl,
    float* __restrict__ Alr, float* __restrict__ Alc, float* __restrict__ Adm)
{
  int b = blockIdx.x, t = threadIdx.x;
  const float* ac  = a_cur  + b*S_D*C_D;
  const float* as_ = a_slot + b*S_D*S_D;
  const float* al  = a_last + b*S_D*C_D;
  const float* ad  = a_dom  + b*S_D*S_D;
  if (t < S_D) {
    float s = 0; for (int c=0;c<C_D;c++) s += ac[t*C_D+c];
    float inv = 1.f/(s+EPS_F);
    for (int c=0;c<C_D;c++) Acr[b*S_D*C_D + t*C_D+c] = ac[t*C_D+c]*inv;
    s = 0; for (int c=0;c<C_D;c++) s += al[t*C_D+c];
    inv = 1.f/(s+EPS_F);
    for (int c=0;c<C_D;c++) Alr[b*S_D*C_D + t*C_D+c] = al[t*C_D+c]*inv;
    s = 0; for (int j=0;j<S_D;j++) s += as_[t*S_D+j];
    inv = 1.f/(s+EPS_F);
    for (int j=0;j<S_D;j++) Asl[b*S_D*S_D + t*S_D+j] = as_[t*S_D+j]*inv;
    s = 0; for (int j=0;j<S_D;j++) s += ad[t*S_D+j];
    inv = 1.f/(s+EPS_F);
    for (int j=0;j<S_D;j++) Adm[b*S_D*S_D + t*S_D+j] = ad[t*S_D+j]*inv;
  } else if (t < S_D + C_D) {
    int c = t - S_D;
    float s = 0; for (int j=0;j<S_D;j++) s += ac[j*C_D+c];
    float inv = 1.f/(s+EPS_F);
    for (int j=0;j<S_D;j++) Acc[b*S_D*C_D + j*C_D+c] = ac[j*C_D+c]*inv;
    s = 0; for (int j=0;j<S_D;j++) s += al[j*C_D+c];
    inv = 1.f/(s+EPS_F);
    for (int j=0;j<S_D;j++) Alc[b*S_D*C_D + j*C_D+c] = al[j*C_D+c]*inv;
  }
}

// ------------------------------------------------------------------
// prep: bf16 transposed weights + folded biases
// W5w  [4608 x 768] : rows n' = seg*768+n; seg 0..4 = Ws,Wr0..3; seg5 = Wg_x
// Wgu  [768 x 768]  : W_g rows 0..767 (u part), transposed
// Wg   [768 x 1536] : full W_g transposed (layer-2 gate)
// Wcat2[768 x 2304] : [Ws; Wr0; Wr2] transposed (layer-2 cls proj)
// ------------------------------------------------------------------
__global__ __launch_bounds__(256) void prep_weights_k(
    const float* __restrict__ W_r, const float* __restrict__ b_r,
    const float* __restrict__ W_s, const float* __restrict__ b_s,
    const float* __restrict__ W_g,
    bf16* __restrict__ W5w, bf16* __restrict__ Wgu, bf16* __restrict__ Wg,
    bf16* __restrict__ Wcat2, float* __restrict__ bslot, float* __restrict__ bcls)
{
  int id = blockIdx.x*256 + threadIdx.x;
  const int n1 = NW*768, n2 = 768*768, n3 = 768*1536, n4 = 768*2304;
  if (id < n1) {
    int np = id / 768, k = id % 768, seg = np / 768, n = np % 768;
    float w;
    if (seg == 0)      w = W_s[k*768 + n];
    else if (seg <= 4) w = W_r[((size_t)(seg-1)*768 + k)*768 + n];
    else               w = W_g[(size_t)(768 + k)*768 + n];
    W5w[id] = __float2bfloat16(w);
  } else if (id < n1 + n2) {
    int j = id - n1; int n = j / 768, k = j % 768;
    Wgu[j] = __float2bfloat16(W_g[(size_t)k*768 + n]);
  } else if (id < n1 + n2 + n3) {
    int j = id - n1 - n2; int n = j / 1536, k = j % 1536;
    Wg[j] = __float2bfloat16(W_g[(size_t)k*768 + n]);
  } else if (id < n1 + n2 + n3 + n4) {
    int j = id - n1 - n2 - n3; int n = j / 2304, k = j % 2304, seg = k / 768, kk = k % 768;
    float w = (seg == 0) ? W_s[kk*768 + n]
            : (seg == 1 ? W_r[(size_t)kk*768 + n] : W_r[((size_t)2*768 + kk)*768 + n]);
    Wcat2[j] = __float2bfloat16(w);
  } else if (id < n1 + n2 + n3 + n4 + 768) {
    int n = id - n1 - n2 - n3 - n4;
    bslot[n] = b_s[n] + b_r[n] + b_r[768+n] + b_r[2*768+n] + b_r[3*768+n];
    bcls[n]  = b_s[n] + b_r[n] + b_r[2*768+n];
  }
}

// ------------------------------------------------------------------
// init: Gin right half <- bf16(inputs). grid (3, 46, chunkB), 256 thr.
// ------------------------------------------------------------------
__global__ __launch_bounds__(256) void init_k(
    const float* __restrict__ slots, const float* __restrict__ cls,
    bf16* __restrict__ Gin, int b0)
{
  int h = blockIdx.x*256 + threadIdx.x;
  int r = blockIdx.y, lb = blockIdx.z, b = b0 + lb;
  float v = (r < S_D) ? slots[((size_t)b*S_D + r)*768 + h]
                      : cls[((size_t)b*C_D + (r - S_D))*768 + h];
  Gin[((size_t)(lb*N_R + r))*1536 + 768 + h] = __float2bfloat16(v);
}

// ------------------------------------------------------------------
// layer-1 aggregation finish: u = Y.seg0 + bias + row-mixes of Y segs.
// One block per batch, 768 threads (thread = output col h).
// Writes Gin left half (u, bf16).
// ------------------------------------------------------------------
__global__ __launch_bounds__(768) void aggfin_k(
    const bf16* __restrict__ Y, bf16* __restrict__ Gin,
    const float* __restrict__ Acr, const float* __restrict__ Acc,
    const float* __restrict__ Asl, const float* __restrict__ Alr,
    const float* __restrict__ Alc, const float* __restrict__ Adm,
    const float* __restrict__ bslot, const float* __restrict__ bcls, int b0)
{
  int lb = blockIdx.x, b = b0 + lb, h = threadIdx.x;
  const bf16* Yb = Y + (size_t)lb*N_R*NW + h;
  bf16* Gb = Gin + (size_t)lb*N_R*1536 + h;
  const float* acr  = Acr + b*480;
  const float* acc_ = Acc + b*480;
  const float* alr  = Alr + b*480;
  const float* alc  = Alc + b*480;
  const float* asl  = Asl + b*900;
  const float* adm  = Adm + b*900;

  // ---- slot rows ----
  {
    float y1c[C_D], y3c[C_D], y2s[S_D], y4s[S_D];
    #pragma unroll
    for (int c = 0; c < C_D; ++c) {
      y1c[c] = __bfloat162float(Yb[(size_t)(S_D+c)*NW + 768]);
      y3c[c] = __bfloat162float(Yb[(size_t)(S_D+c)*NW + 2304]);
    }
    #pragma unroll
    for (int s = 0; s < S_D; ++s) {
      y2s[s] = __bfloat162float(Yb[(size_t)s*NW + 1536]);
      y4s[s] = __bfloat162float(Yb[(size_t)s*NW + 3072]);
    }
    #pragma unroll 1
    for (int s = 0; s < S_D; ++s) {
      float u = __bfloat162float(Yb[(size_t)s*NW]) + bslot[h];
      #pragma unroll
      for (int c = 0; c < C_D; ++c) { u += acr[s*C_D + c]*y1c[c] + alr[s*C_D + c]*y3c[c]; }
      #pragma unroll
      for (int t = 0; t < S_D; ++t) { u += asl[s*S_D + t]*y2s[t] + adm[s*S_D + t]*y4s[t]; }
      Gb[(size_t)s*1536] = __float2bfloat16(u);
    }
  }
  // ---- cls rows ----
  {
    float y1s[S_D], y3s[S_D];
    #pragma unroll
    for (int s = 0; s < S_D; ++s) {
      y1s[s] = __bfloat162float(Yb[(size_t)s*NW + 768]);
      y3s[s] = __bfloat162float(Yb[(size_t)s*NW + 2304]);
    }
    #pragma unroll 1
    for (int c = 0; c < C_D; ++c) {
      float u = __bfloat162float(Yb[(size_t)(S_D+c)*NW]) + bcls[h];
      #pragma unroll
      for (int s = 0; s < S_D; ++s) { u += acc_[s*C_D + c]*y1s[s] + alc[s*C_D + c]*y3s[s]; }
      Gb[(size_t)(S_D+c)*1536] = __float2bfloat16(u);
    }
  }
}

// ------------------------------------------------------------------
// layer-2 aggregation (cls rows only). X = layer-1 state (f32).
// Writes Z2 (2 segs, stride 1536) and Gin right half (cls x, bf16).
// ------------------------------------------------------------------
__global__ __launch_bounds__(768) void aggregate2_k(
    const float* __restrict__ X, bf16* __restrict__ Z2, bf16* __restrict__ Gin2,
    const float* __restrict__ Acc, const float* __restrict__ Alc, int b0)
{
  int lb = blockIdx.x, b = b0 + lb, h = threadIdx.x;
  const float* Xb = X + (size_t)lb*N_R*768;
  float xs[S_D];
  #pragma unroll
  for (int s = 0; s < S_D; ++s) xs[s] = Xb[s*768 + h];
  const float* acc_ = Acc + b*480;
  const float* alc  = Alc + b*480;
  #pragma unroll 1
  for (int c = 0; c < C_D; ++c) {
    float v = Xb[(S_D + c)*768 + h];
    float a1 = 0, a3 = 0;
    #pragma unroll
    for (int s = 0; s < S_D; ++s) { a1 += acc_[s*C_D + c]*xs[s]; a3 += alc[s*C_D + c]*xs[s]; }
    size_t r2 = (size_t)lb*C_D + c;
    Z2[r2*1536 + h]          = __float2bfloat16(a1);
    Z2[r2*1536 + 768 + h]    = __float2bfloat16(a3);
    Gin2[r2*1536 + 768 + h]  = __float2bfloat16(v);
  }
}

// ------------------------------------------------------------------
// MFMA GEMM: C[M x N_] = A[M x K] @ Bt[N_ x K]^T. 128x128 tile, BK=64,
// T2 both-sides XOR swizzle, T1 bijective XCD swizzle, and 2-phase
// double-buffer prefetch (stage(next) -> compute(cur) -> syncthreads;
// the vmcnt(0) at the barrier lands AFTER compute, so the prefetch
// flies under the MFMA phase).
// A dual-source: cols [0,SK) from A0 (stride LDA0), [SK,K) from A1.
// EPI 0: wide proj  -> Y bf16 (stride NW)
// EPI 2: gate layer1 -> X f32 (x_old from original inputs; gate-x term
//                      precomputed in Y cols [3840,4608))
// EPI 3: proj layer2 -> Gin left (bf16) + bias_cls
// EPI 4: gate layer2 -> final cls -> out
// ------------------------------------------------------------------
template<int K, int N_, int EPI, int LDA0, int LDA1, int SK>
__global__ __launch_bounds__(256) void gemm_k(
    const bf16* __restrict__ A0, const bf16* __restrict__ A1,
    const bf16* __restrict__ Bt, bf16* __restrict__ G,
    bf16* __restrict__ Y,
    const float* __restrict__ bias_slot, const float* __restrict__ bias_cls,
    const float* __restrict__ bg, float* __restrict__ X,
    float* __restrict__ out,
    const float* __restrict__ slots, const float* __restrict__ cls, int b0)
{
  __shared__ __align__(16) bf16 As[2][128*64];
  __shared__ __align__(16) bf16 Bs[2][128*64];
  const int tid  = threadIdx.x;
  const int lane = tid & 63;
  const int wave = tid >> 6;
  const int wm = wave >> 1, wn = wave & 1;
  const int NBN = N_/128;

  // T1: bijective XCD-chunked swizzle (m204)
  const int nwg = gridDim.x;
  const int q = nwg >> 3, r = nwg & 7;
  const int xcd = blockIdx.x & 7, idx = blockIdx.x >> 3;
  const int wg = (xcd < r ? xcd*(q+1) : r*(q+1) + (xcd-r)*q) + idx;
  const int bm = wg / NBN, bn = wg % NBN;

  // T2 write side: pre-swizzled global source slot, linear LDS dest.
  const int swz = (((tid & 7) ^ ((tid >> 3) & 7))) << 3;   // elements
  const bf16* Ag0 = A0 + (size_t)(bm*128 + (tid>>3))*LDA0 + swz;
  const bf16* Ag1 = A1 + (size_t)(bm*128 + (tid>>3))*LDA1 + swz;
  const bf16* Bg  = Bt + (size_t)(bn*128 + (tid>>3))*K    + swz;
  const int ldsw = (wave*8)*64;

  f32x4 acc[4][4] = {};
  const int NT = K/64;

  auto stage = [&](int buf, int kt) {
    #pragma unroll
    for (int p = 0; p < 4; ++p) {
      const bf16* asrc = (kt < SK) ? (Ag0 + (size_t)(p*32)*LDA0 + kt)
                                   : (Ag1 + (size_t)(p*32)*LDA1 + (kt - SK));
      __builtin_amdgcn_global_load_lds(
        (const __attribute__((address_space(1))) void*)asrc,
        (__attribute__((address_space(3))) void*)(&As[buf][ldsw + p*32*64]), 16, 0, 0);
      __builtin_amdgcn_global_load_lds(
        (const __attribute__((address_space(1))) void*)(Bg + (size_t)(p*32)*K + kt),
        (__attribute__((address_space(3))) void*)(&Bs[buf][ldsw + p*32*64]), 16, 0, 0);
    }
  };

  stage(0, 0);
  __syncthreads();
  int cur = 0;
  #pragma unroll 1
  for (int t = 0; t < NT; ++t) {
    if (t + 1 < NT) stage(cur ^ 1, (t + 1)*64);   // prefetch flies under MFMA
    const bf16* Asb = As[cur];
    const bf16* Bsb = Bs[cur];
    #pragma unroll
    for (int ks = 0; ks < 64; ks += 32) {
      bf16x8 af[4], bfv[4];
      const int sa = ((((ks >> 3) + (lane >> 4)) ^ (lane & 7))) << 3;
      #pragma unroll
      for (int i = 0; i < 4; ++i) {
        int m = wm*64 + i*16 + (lane & 15);
        af[i]  = *(const bf16x8*)&Asb[m*64 + sa];
        int n = wn*64 + i*16 + (lane & 15);
        bfv[i] = *(const bf16x8*)&Bsb[n*64 + sa];
      }
      #pragma unroll
      for (int i = 0; i < 4; ++i)
        #pragma unroll
        for (int j = 0; j < 4; ++j)
          acc[i][j] = __builtin_amdgcn_mfma_f32_16x16x32_bf16(af[i], bfv[j], acc[i][j], 0, 0, 0);
    }
    __syncthreads();   // vmcnt(0)+barrier AFTER compute: prefetch has landed
    cur ^= 1;
  }

  const int rbase = bm*128 + wm*64 + ((lane>>4)<<2);
  const int cbase = bn*128 + wn*64 + (lane & 15);
  #pragma unroll
  for (int i = 0; i < 4; ++i) {
    #pragma unroll
    for (int j = 0; j < 4; ++j) {
      const int col = cbase + j*16;
      #pragma unroll
      for (int r2 = 0; r2 < 4; ++r2) {
        const int row = rbase + i*16 + r2;
        float v = acc[i][j][r2];
        if constexpr (EPI == 0) {
          Y[(size_t)row*NW + col] = __float2bfloat16(v);
        } else if constexpr (EPI == 2) {
          v += bg[col] + __bfloat162float(Y[(size_t)row*NW + 3840 + col]);
          float g = 1.f/(1.f + __expf(-v));
          float u = __bfloat162float(G[(size_t)row*1536 + col]);
          int lb2 = row / N_R, rb = row - lb2*N_R;
          float xo = (rb < S_D)
            ? slots[((size_t)(b0+lb2)*S_D + rb)*768 + col]
            : cls[((size_t)(b0+lb2)*C_D + (rb - S_D))*768 + col];
          X[(size_t)row*H_D + col] = fmaxf(u, 0.f)*g + xo*(1.f - g);
        } else if constexpr (EPI == 3) {
          v += bias_cls[col];
          G[(size_t)row*1536 + col] = __float2bfloat16(v);
        } else { // EPI == 4: final cls gate -> out
          v += bg[col];
          float g = 1.f/(1.f + __expf(-v));
          float u = __bfloat162float(G[(size_t)row*1536 + col]);
          int lb2 = row >> 4, c = row & 15;
          if (c >= 1) {
            float xo = X[((size_t)lb2*N_R + S_D + c)*H_D + col];
            out[((size_t)(b0 + lb2)*15 + (c - 1))*H_D + col] =
                fmaxf(u, 0.f)*g + xo*(1.f - g);
          }
        }
      }
    }
  }
}

// ------------------------------------------------------------------
extern "C" void kernel_launch(void* const* d_in, const int* in_sizes, int n_in,
                              void* d_out, int out_size, void* d_ws, size_t ws_size,
                              hipStream_t stream)
{
  const float* slots  = (const float*)d_in[0];
  const float* cls    = (const float*)d_in[1];
  const float* a_cur  = (const float*)d_in[2];
  const float* a_slot = (const float*)d_in[3];
  const float* a_last = (const float*)d_in[4];
  const float* a_dom  = (const float*)d_in[5];
  const float* W_r    = (const float*)d_in[6];
  const float* b_r    = (const float*)d_in[7];
  const float* W_s    = (const float*)d_in[8];
  const float* b_s    = (const float*)d_in[9];
  const float* W_g    = (const float*)d_in[10];
  const float* b_g    = (const float*)d_in[11];
  float* out = (float*)d_out;

  char* base = (char*)d_ws;
  size_t off = 0;
  auto alloc = [&](size_t bytes) -> void* {
    void* r = base + off;
    off = (off + bytes + 255) & ~(size_t)255;
    return r;
  };

  float* Acr = (float*)alloc((size_t)512*480*4);
  float* Acc = (float*)alloc((size_t)512*480*4);
  float* Alr = (float*)alloc((size_t)512*480*4);
  float* Alc = (float*)alloc((size_t)512*480*4);
  float* Asl = (float*)alloc((size_t)512*900*4);
  float* Adm = (float*)alloc((size_t)512*900*4);
  bf16* W5w   = (bf16*)alloc((size_t)NW*768*2);
  bf16* Wgu   = (bf16*)alloc((size_t)768*768*2);
  bf16* Wg    = (bf16*)alloc((size_t)768*1536*2);
  bf16* Wcat2 = (bf16*)alloc((size_t)768*2304*2);
  float* bslot = (float*)alloc(768*4);
  float* bcls  = (float*)alloc(768*4);
  size_t fixedOff = off;

  // per-batch: X f32 + Gin bf16 (46x1536) + Y bf16 (46x4608) + Z2 (16x1536)
  const size_t perBatch = (size_t)N_R*H_D*4
                        + (size_t)N_R*1536*2
                        + (size_t)N_R*NW*2
                        + (size_t)C_D*1536*2;
  int chunkB = 512;
  while (chunkB > 64 && fixedOff + perBatch*chunkB + 65536 > ws_size) chunkB >>= 1;

  const int rows = chunkB * N_R;
  float* X   = (float*)alloc((size_t)rows*H_D*4);
  bf16* Gin  = (bf16*)alloc((size_t)rows*1536*2);
  bf16* Y    = (bf16*)alloc((size_t)rows*NW*2);
  bf16* Z2   = (bf16*)alloc((size_t)chunkB*C_D*1536*2);

  prep_norm_k<<<512, 64, 0, stream>>>(a_cur, a_slot, a_last, a_dom,
                                      Acr, Acc, Asl, Alr, Alc, Adm);
  {
    int tot = NW*768 + 768*768 + 768*1536 + 768*2304 + 768;
    prep_weights_k<<<(tot+255)/256, 256, 0, stream>>>(W_r, b_r, W_s, b_s, W_g,
                                                      W5w, Wgu, Wg, Wcat2, bslot, bcls);
  }

  for (int b0 = 0; b0 < 512; b0 += chunkB) {
    const int rows2 = chunkB * C_D;
    // ---- layer 1 ----
    init_k<<<dim3(3, N_R, chunkB), 256, 0, stream>>>(slots, cls, Gin, b0);
    // wide proj: Y = x @ [Ws|Wr0..3|Wg_x], K=768, N=4608
    gemm_k<768, NW, 0, 1536, 1536, 768><<<(rows/128)*(NW/128), 256, 0, stream>>>(
        Gin + 768, Gin + 768, W5w, nullptr, Y, bslot, bcls, b_g, X, out, slots, cls, b0);
    aggfin_k<<<chunkB, 768, 0, stream>>>(Y, Gin, Acr, Acc, Asl, Alr, Alc, Adm,
                                         bslot, bcls, b0);
    // gate: u @ Wg_u (+ precomputed x@Wg_x from Y) -> X
    gemm_k<768, 768, 2, 1536, 1536, 768><<<(rows/128)*6, 256, 0, stream>>>(
        Gin, Gin, Wgu, Gin, Y, bslot, bcls, b_g, X, out, slots, cls, b0);
    // ---- layer 2 (cls rows only) ----
    aggregate2_k<<<chunkB, 768, 0, stream>>>(X, Z2, Gin, Acc, Alc, b0);
    gemm_k<2304, 768, 3, 1536, 1536, 768><<<(rows2/128)*6, 256, 0, stream>>>(
        Gin + 768, Z2, Wcat2, Gin, Y, bslot, bcls, b_g, X, out, slots, cls, b0);
    gemm_k<1536, 768, 4, 1536, 1536, 1536><<<(rows2/128)*6, 256, 0, stream>>>(
        Gin, Gin, Wg, Gin, Y, bslot, bcls, b_g, X, out, slots, cls, b0);
  }
}

// Round 5
// 615.352 us; speedup vs baseline: 1.4655x; 1.4655x over previous
//
#include <hip/hip_runtime.h>
#include <hip/hip_bf16.h>
#include <cstdint>
#include <cstddef>

typedef __hip_bfloat16 bf16;
typedef __bf16 bf16x8 __attribute__((ext_vector_type(8)));
typedef float f32x4 __attribute__((ext_vector_type(4)));

#define S_D 30
#define C_D 16
#define H_D 768
#define EPS_F 1e-5f
#define ISTR 160   // per-batch stride of inv-sum table (floats)

// ------------------------------------------------------------------
// prep: inverse row/col sums of the adjacency matrices (layer-invariant)
// layout per batch: [0,30) inv_rowsum(a_cur), [30,60) inv_rowsum(a_last),
// [60,90) inv_rowsum(a_slot), [90,120) inv_rowsum(a_dom),
// [120,136) inv_colsum(a_cur), [136,152) inv_colsum(a_last)
// ------------------------------------------------------------------
__global__ __launch_bounds__(64) void prep_sums_k(
    const float* __restrict__ a_cur, const float* __restrict__ a_slot,
    const float* __restrict__ a_last, const float* __restrict__ a_dom,
    float* __restrict__ ISum)
{
  int b = blockIdx.x, t = threadIdx.x;
  const float* ac  = a_cur  + (size_t)b*S_D*C_D;
  const float* as_ = a_slot + (size_t)b*S_D*S_D;
  const float* al  = a_last + (size_t)b*S_D*C_D;
  const float* ad  = a_dom  + (size_t)b*S_D*S_D;
  float* iv = ISum + (size_t)b*ISTR;
  if (t < S_D) {
    float s1 = 0, s2 = 0, s3 = 0, s4 = 0;
    for (int c = 0; c < C_D; ++c) { s1 += ac[t*C_D+c]; s3 += al[t*C_D+c]; }
    for (int j = 0; j < S_D; ++j) { s2 += as_[t*S_D+j]; s4 += ad[t*S_D+j]; }
    iv[t]      = 1.f/(s1 + EPS_F);
    iv[30 + t] = 1.f/(s3 + EPS_F);
    iv[60 + t] = 1.f/(s2 + EPS_F);
    iv[90 + t] = 1.f/(s4 + EPS_F);
  } else if (t < S_D + C_D) {
    int c = t - S_D;
    float s1 = 0, s3 = 0;
    for (int s = 0; s < S_D; ++s) { s1 += ac[s*C_D+c]; s3 += al[s*C_D+c]; }
    iv[120 + c] = 1.f/(s1 + EPS_F);
    iv[136 + c] = 1.f/(s3 + EPS_F);
  }
}

// ------------------------------------------------------------------
// prep: bf16 transposed weight concats + folded biases
// Wcat  [768n x 3840k] : [W_s; W_r0; W_r1; W_r2; W_r3]^T   (slot proj)
// Wg    [768n x 1536k] : W_g^T                              (gates)
// Wcat2 [768n x 2304k] : [W_s; W_r0; W_r2]^T                (cls proj)
// ------------------------------------------------------------------
__global__ __launch_bounds__(256) void prep_weights_k(
    const float* __restrict__ W_r, const float* __restrict__ b_r,
    const float* __restrict__ W_s, const float* __restrict__ b_s,
    const float* __restrict__ W_g,
    bf16* __restrict__ Wcat, bf16* __restrict__ Wg, bf16* __restrict__ Wcat2,
    float* __restrict__ bslot, float* __restrict__ bcls)
{
  int id = blockIdx.x*256 + threadIdx.x;
  const int n1 = 768*3840, n2 = 768*1536, n3 = 768*2304;
  if (id < n1) {
    int n = id / 3840, k = id % 3840, seg = k / 768, kk = k % 768;
    float w = (seg == 0) ? W_s[kk*768 + n] : W_r[((size_t)(seg-1)*768 + kk)*768 + n];
    Wcat[id] = __float2bfloat16(w);
  } else if (id < n1 + n2) {
    int j = id - n1; int n = j / 1536, k = j % 1536;
    Wg[j] = __float2bfloat16(W_g[(size_t)k*768 + n]);
  } else if (id < n1 + n2 + n3) {
    int j = id - n1 - n2; int n = j / 2304, k = j % 2304, seg = k / 768, kk = k % 768;
    float w = (seg == 0) ? W_s[kk*768 + n]
            : (seg == 1 ? W_r[(size_t)kk*768 + n] : W_r[((size_t)2*768 + kk)*768 + n]);
    Wcat2[j] = __float2bfloat16(w);
  } else if (id < n1 + n2 + n3 + 768) {
    int n = id - n1 - n2 - n3;
    bslot[n] = b_s[n] + b_r[n] + b_r[768+n] + b_r[2*768+n] + b_r[3*768+n];
    bcls[n]  = b_s[n] + b_r[n] + b_r[2*768+n];
  }
}

// ------------------------------------------------------------------
// layer-1 aggregation + init. One block per batch, 768 threads (= col h).
// Row spaces are SPLIT: slot rows [0, cB*30), cls rows [rsBase, +cB*16).
// Writes: Gin right halves (x, bf16), Zs (4 slot agg segs, stride 3072),
// Zc (2 cls agg segs, stride 1536). Normalizers folded via ISum.
// ------------------------------------------------------------------
__global__ __launch_bounds__(768) void agg1_k(
    const float* __restrict__ slots, const float* __restrict__ cls,
    const float* __restrict__ a_cur, const float* __restrict__ a_slot,
    const float* __restrict__ a_last, const float* __restrict__ a_dom,
    const float* __restrict__ ISum,
    bf16* __restrict__ Gin, bf16* __restrict__ Zs, bf16* __restrict__ Zc,
    int b0, int rsBase)
{
  int lb = blockIdx.x, b = b0 + lb, h = threadIdx.x;
  float xs[S_D], xc[C_D];
  #pragma unroll
  for (int s = 0; s < S_D; ++s) xs[s] = slots[((size_t)b*S_D + s)*768 + h];
  #pragma unroll
  for (int c = 0; c < C_D; ++c) xc[c] = cls[((size_t)b*C_D + c)*768 + h];

  bf16* Gs = Gin + ((size_t)lb*S_D)*1536 + 768 + h;
  #pragma unroll
  for (int s = 0; s < S_D; ++s) Gs[(size_t)s*1536] = __float2bfloat16(xs[s]);
  bf16* Gc = Gin + ((size_t)(rsBase + lb*C_D))*1536 + 768 + h;
  #pragma unroll
  for (int c = 0; c < C_D; ++c) Gc[(size_t)c*1536] = __float2bfloat16(xc[c]);

  const float* ac  = a_cur  + (size_t)b*S_D*C_D;
  const float* as_ = a_slot + (size_t)b*S_D*S_D;
  const float* al  = a_last + (size_t)b*S_D*C_D;
  const float* ad  = a_dom  + (size_t)b*S_D*S_D;
  const float* iv  = ISum + (size_t)b*ISTR;

  bf16* Zsr = Zs + ((size_t)lb*S_D)*3072 + h;
  #pragma unroll 1
  for (int s = 0; s < S_D; ++s) {
    float a1 = 0, a2 = 0, a3 = 0, a4 = 0;
    #pragma unroll
    for (int c = 0; c < C_D; ++c) { a1 += ac[s*C_D + c]*xc[c]; a3 += al[s*C_D + c]*xc[c]; }
    #pragma unroll
    for (int t = 0; t < S_D; ++t) { a2 += as_[s*S_D + t]*xs[t]; a4 += ad[s*S_D + t]*xs[t]; }
    bf16* row = Zsr + (size_t)s*3072;
    row[0]    = __float2bfloat16(a1*iv[s]);
    row[768]  = __float2bfloat16(a2*iv[60+s]);
    row[1536] = __float2bfloat16(a3*iv[30+s]);
    row[2304] = __float2bfloat16(a4*iv[90+s]);
  }
  bf16* Zcr = Zc + ((size_t)lb*C_D)*1536 + h;
  #pragma unroll 1
  for (int c = 0; c < C_D; ++c) {
    float a1 = 0, a3 = 0;
    #pragma unroll
    for (int s = 0; s < S_D; ++s) { a1 += ac[s*C_D + c]*xs[s]; a3 += al[s*C_D + c]*xs[s]; }
    Zcr[(size_t)c*1536]       = __float2bfloat16(a1*iv[120+c]);
    Zcr[(size_t)c*1536 + 768] = __float2bfloat16(a3*iv[136+c]);
  }
}

// ------------------------------------------------------------------
// layer-2 aggregation (cls rows only), from layer-1 state Xo (bf16).
// Writes Zc (2 segs) and Gin cls right half (new cls x).
// ------------------------------------------------------------------
__global__ __launch_bounds__(768) void agg2_k(
    const bf16* __restrict__ Xo,
    const float* __restrict__ a_cur, const float* __restrict__ a_last,
    const float* __restrict__ ISum,
    bf16* __restrict__ Gin, bf16* __restrict__ Zc, int b0, int rsBase)
{
  int lb = blockIdx.x, b = b0 + lb, h = threadIdx.x;
  float xs[S_D];
  #pragma unroll
  for (int s = 0; s < S_D; ++s)
    xs[s] = __bfloat162float(Xo[((size_t)(lb*S_D + s))*768 + h]);

  const float* ac = a_cur  + (size_t)b*S_D*C_D;
  const float* al = a_last + (size_t)b*S_D*C_D;
  const float* iv = ISum + (size_t)b*ISTR;

  const bf16* Xc = Xo + ((size_t)(rsBase + lb*C_D))*768 + h;
  bf16* Gc  = Gin + ((size_t)(rsBase + lb*C_D))*1536 + 768 + h;
  bf16* Zcr = Zc + ((size_t)lb*C_D)*1536 + h;
  #pragma unroll 1
  for (int c = 0; c < C_D; ++c) {
    float a1 = 0, a3 = 0;
    #pragma unroll
    for (int s = 0; s < S_D; ++s) { a1 += ac[s*C_D + c]*xs[s]; a3 += al[s*C_D + c]*xs[s]; }
    Zcr[(size_t)c*1536]       = __float2bfloat16(a1*iv[120+c]);
    Zcr[(size_t)c*1536 + 768] = __float2bfloat16(a3*iv[136+c]);
    Gc[(size_t)c*1536] = Xc[(size_t)c*768];
  }
}

// ------------------------------------------------------------------
// MFMA GEMM: C[M x 768] = A[M x K] @ Bt[768 x K]^T. 128x128 tile, BK=64.
// T2 both-sides XOR swizzle (write side: pre-swizzled global slot,
// linear global_load_lds dest; read side: XOR'd ds_read) + T1 bijective
// XCD swizzle + 2-phase LDS double-buffer prefetch.
// A dual-source: cols [0,SK) from A0 (stride LDA0), [SK,K) from A1.
// EPI 0: proj -> G left half  = bf16(v + bias[col])
// EPI 1: gate -> Xo bf16      = relu(u)*g + x*(1-g), u/x from G halves
// EPI 2: gate -> out f32      (cls rows; skip c==0)
// ------------------------------------------------------------------
template<int K, int EPI, int LDA0, int LDA1, int SK>
__global__ __launch_bounds__(256) void gemm_k(
    const bf16* __restrict__ A0, const bf16* __restrict__ A1,
    const bf16* __restrict__ Bt, bf16* __restrict__ G,
    bf16* __restrict__ Xo, float* __restrict__ out,
    const float* __restrict__ bias, const float* __restrict__ bg, int b0)
{
  __shared__ __align__(16) bf16 As[2][128*64];
  __shared__ __align__(16) bf16 Bs[2][128*64];
  const int tid  = threadIdx.x;
  const int lane = tid & 63;
  const int wave = tid >> 6;
  const int wm = wave >> 1, wn = wave & 1;

  // T1: bijective XCD-chunked swizzle (m204)
  const int nwg = gridDim.x;
  const int q = nwg >> 3, r = nwg & 7;
  const int xcd = blockIdx.x & 7, idx = blockIdx.x >> 3;
  const int wg = (xcd < r ? xcd*(q+1) : r*(q+1) + (xcd-r)*q) + idx;
  const int bm = wg / 6, bn = wg % 6;

  // T2 write side: pre-swizzled global source slot, linear LDS dest.
  const int swz = (((tid & 7) ^ ((tid >> 3) & 7))) << 3;   // elements
  const bf16* Ag0 = A0 + (size_t)(bm*128 + (tid>>3))*LDA0 + swz;
  const bf16* Ag1 = A1 + (size_t)(bm*128 + (tid>>3))*LDA1 + swz;
  const bf16* Bg  = Bt + (size_t)(bn*128 + (tid>>3))*K    + swz;
  const int ldsw = (wave*8)*64;

  f32x4 acc[4][4] = {};
  const int NT = K/64;

  auto stage = [&](int buf, int kt) {
    #pragma unroll
    for (int p = 0; p < 4; ++p) {
      const bf16* asrc = (kt < SK) ? (Ag0 + (size_t)(p*32)*LDA0 + kt)
                                   : (Ag1 + (size_t)(p*32)*LDA1 + (kt - SK));
      __builtin_amdgcn_global_load_lds(
        (const __attribute__((address_space(1))) void*)asrc,
        (__attribute__((address_space(3))) void*)(&As[buf][ldsw + p*32*64]), 16, 0, 0);
      __builtin_amdgcn_global_load_lds(
        (const __attribute__((address_space(1))) void*)(Bg + (size_t)(p*32)*K + kt),
        (__attribute__((address_space(3))) void*)(&Bs[buf][ldsw + p*32*64]), 16, 0, 0);
    }
  };

  stage(0, 0);
  __syncthreads();
  int cur = 0;
  #pragma unroll 1
  for (int t = 0; t < NT; ++t) {
    if (t + 1 < NT) stage(cur ^ 1, (t + 1)*64);   // prefetch flies under MFMA
    const bf16* Asb = As[cur];
    const bf16* Bsb = Bs[cur];
    #pragma unroll
    for (int ks = 0; ks < 64; ks += 32) {
      bf16x8 af[4], bfv[4];
      const int sa = ((((ks >> 3) + (lane >> 4)) ^ (lane & 7))) << 3;
      #pragma unroll
      for (int i = 0; i < 4; ++i) {
        int m = wm*64 + i*16 + (lane & 15);
        af[i]  = *(const bf16x8*)&Asb[m*64 + sa];
        int n = wn*64 + i*16 + (lane & 15);
        bfv[i] = *(const bf16x8*)&Bsb[n*64 + sa];
      }
      #pragma unroll
      for (int i = 0; i < 4; ++i)
        #pragma unroll
        for (int j = 0; j < 4; ++j)
          acc[i][j] = __builtin_amdgcn_mfma_f32_16x16x32_bf16(af[i], bfv[j], acc[i][j], 0, 0, 0);
    }
    __syncthreads();   // vmcnt(0)+barrier after compute: prefetch has landed
    cur ^= 1;
  }

  const int rbase = bm*128 + wm*64 + ((lane>>4)<<2);
  const int cbase = bn*128 + wn*64 + (lane & 15);
  #pragma unroll
  for (int i = 0; i < 4; ++i) {
    #pragma unroll
    for (int j = 0; j < 4; ++j) {
      const int col = cbase + j*16;
      #pragma unroll
      for (int r2 = 0; r2 < 4; ++r2) {
        const int row = rbase + i*16 + r2;
        float v = acc[i][j][r2];
        if constexpr (EPI == 0) {
          G[(size_t)row*1536 + col] = __float2bfloat16(v + bias[col]);
        } else if constexpr (EPI == 1) {
          v += bg[col];
          float g = 1.f/(1.f + __expf(-v));
          float u = __bfloat162float(G[(size_t)row*1536 + col]);
          float x = __bfloat162float(G[(size_t)row*1536 + 768 + col]);
          Xo[(size_t)row*H_D + col] = __float2bfloat16(fmaxf(u, 0.f)*g + x*(1.f - g));
        } else { // EPI == 2: final cls gate -> out
          v += bg[col];
          float g = 1.f/(1.f + __expf(-v));
          float u = __bfloat162float(G[(size_t)row*1536 + col]);
          int bb = row >> 4, c = row & 15;
          if (c >= 1) {
            float x = __bfloat162float(Xo[(size_t)row*H_D + col]);
            out[((size_t)(b0 + bb)*15 + (c - 1))*H_D + col] =
                fmaxf(u, 0.f)*g + x*(1.f - g);
          }
        }
      }
    }
  }
}

// ------------------------------------------------------------------
extern "C" void kernel_launch(void* const* d_in, const int* in_sizes, int n_in,
                              void* d_out, int out_size, void* d_ws, size_t ws_size,
                              hipStream_t stream)
{
  const float* slots  = (const float*)d_in[0];
  const float* cls    = (const float*)d_in[1];
  const float* a_cur  = (const float*)d_in[2];
  const float* a_slot = (const float*)d_in[3];
  const float* a_last = (const float*)d_in[4];
  const float* a_dom  = (const float*)d_in[5];
  const float* W_r    = (const float*)d_in[6];
  const float* b_r    = (const float*)d_in[7];
  const float* W_s    = (const float*)d_in[8];
  const float* b_s    = (const float*)d_in[9];
  const float* W_g    = (const float*)d_in[10];
  const float* b_g    = (const float*)d_in[11];
  float* out = (float*)d_out;

  char* base = (char*)d_ws;
  size_t off = 0;
  auto alloc = [&](size_t bytes) -> void* {
    void* r = base + off;
    off = (off + bytes + 255) & ~(size_t)255;
    return r;
  };

  float* ISum  = (float*)alloc((size_t)512*ISTR*4);
  bf16* Wcat   = (bf16*)alloc((size_t)768*3840*2);
  bf16* Wg     = (bf16*)alloc((size_t)768*1536*2);
  bf16* Wcat2  = (bf16*)alloc((size_t)768*2304*2);
  float* bslot = (float*)alloc(768*4);
  float* bcls  = (float*)alloc(768*4);
  size_t fixedOff = off;

  // per-batch: Gin [46x1536] + Xo [46x768] + Zs [30x3072] + Zc [16x1536], all bf16
  const size_t perBatch = (size_t)46*1536*2 + (size_t)46*768*2
                        + (size_t)30*3072*2 + (size_t)16*1536*2;
  int chunkB = 512;
  while (chunkB > 64 && fixedOff + perBatch*(size_t)chunkB + 65536 > ws_size) chunkB >>= 1;

  const int rows_s = chunkB * S_D;       // slot rows
  const int rows_c = chunkB * C_D;       // cls rows
  const int rows_a = chunkB * (S_D + C_D);
  bf16* Gin = (bf16*)alloc((size_t)rows_a*1536*2);
  bf16* Xo  = (bf16*)alloc((size_t)rows_a*768*2);
  bf16* Zs  = (bf16*)alloc((size_t)rows_s*3072*2);
  bf16* Zc  = (bf16*)alloc((size_t)rows_c*1536*2);
  bf16* GinC = Gin + (size_t)rows_s*1536;
  bf16* XoC  = Xo  + (size_t)rows_s*768;

  prep_sums_k<<<512, 64, 0, stream>>>(a_cur, a_slot, a_last, a_dom, ISum);
  {
    int tot = 768*3840 + 768*1536 + 768*2304 + 768;
    prep_weights_k<<<(tot+255)/256, 256, 0, stream>>>(W_r, b_r, W_s, b_s, W_g,
                                                      Wcat, Wg, Wcat2, bslot, bcls);
  }

  for (int b0 = 0; b0 < 512; b0 += chunkB) {
    // ---- layer 1 ----
    agg1_k<<<chunkB, 768, 0, stream>>>(slots, cls, a_cur, a_slot, a_last, a_dom,
                                       ISum, Gin, Zs, Zc, b0, rows_s);
    // slot proj: A = [x | Zs], K=3840 -> Gin_s left (u + bslot)
    gemm_k<3840, 0, 1536, 3072, 768><<<(rows_s/128)*6, 256, 0, stream>>>(
        Gin + 768, Zs, Wcat, Gin, Xo, out, bslot, b_g, b0);
    // cls proj: A = [x | Zc], K=2304 -> Gin_c left (u + bcls)
    gemm_k<2304, 0, 1536, 1536, 768><<<(rows_c/128)*6, 256, 0, stream>>>(
        GinC + 768, Zc, Wcat2, GinC, XoC, out, bcls, b_g, b0);
    // gate (all rows): A = Gin = [u | x], K=1536 -> Xo bf16
    gemm_k<1536, 1, 1536, 1536, 1536><<<(rows_a/128)*6, 256, 0, stream>>>(
        Gin, Gin, Wg, Gin, Xo, out, bslot, b_g, b0);
    // ---- layer 2 (cls rows only) ----
    agg2_k<<<chunkB, 768, 0, stream>>>(Xo, a_cur, a_last, ISum, Gin, Zc, b0, rows_s);
    gemm_k<2304, 0, 1536, 1536, 768><<<(rows_c/128)*6, 256, 0, stream>>>(
        GinC + 768, Zc, Wcat2, GinC, XoC, out, bcls, b_g, b0);
    // final gate -> out
    gemm_k<1536, 2, 1536, 1536, 1536><<<(rows_c/128)*6, 256, 0, stream>>>(
        GinC, GinC, Wg, GinC, XoC, out, bcls, b_g, b0);
  }
}

// Round 6
// 565.972 us; speedup vs baseline: 1.5934x; 1.0872x over previous
//
#include <hip/hip_runtime.h>
#include <hip/hip_bf16.h>
#include <cstdint>
#include <cstddef>

typedef __hip_bfloat16 bf16;
typedef __bf16 bf16x8 __attribute__((ext_vector_type(8)));
typedef float f32x4 __attribute__((ext_vector_type(4)));

#define S_D 30
#define C_D 16
#define H_D 768
#define EPS_F 1e-5f

// ------------------------------------------------------------------
// prep: normalized adjacency matrices (layer-invariant)
// ------------------------------------------------------------------
__global__ __launch_bounds__(64) void prep_norm_k(
    const float* __restrict__ a_cur, const float* __restrict__ a_slot,
    const float* __restrict__ a_last, const float* __restrict__ a_dom,
    float* __restrict__ Acr, float* __restrict__ Acc, float* __restrict__ Asl,
    float* __restrict__ Alr, float* __restrict__ Alc, float* __restrict__ Adm)
{
  int b = blockIdx.x, t = threadIdx.x;
  const float* ac  = a_cur  + (size_t)b*S_D*C_D;
  const float* as_ = a_slot + (size_t)b*S_D*S_D;
  const float* al  = a_last + (size_t)b*S_D*C_D;
  const float* ad  = a_dom  + (size_t)b*S_D*S_D;
  if (t < S_D) {
    float s = 0; for (int c=0;c<C_D;c++) s += ac[t*C_D+c];
    float inv = 1.f/(s+EPS_F);
    for (int c=0;c<C_D;c++) Acr[(size_t)b*480 + t*C_D+c] = ac[t*C_D+c]*inv;
    s = 0; for (int c=0;c<C_D;c++) s += al[t*C_D+c];
    inv = 1.f/(s+EPS_F);
    for (int c=0;c<C_D;c++) Alr[(size_t)b*480 + t*C_D+c] = al[t*C_D+c]*inv;
    s = 0; for (int j=0;j<S_D;j++) s += as_[t*S_D+j];
    inv = 1.f/(s+EPS_F);
    for (int j=0;j<S_D;j++) Asl[(size_t)b*900 + t*S_D+j] = as_[t*S_D+j]*inv;
    s = 0; for (int j=0;j<S_D;j++) s += ad[t*S_D+j];
    inv = 1.f/(s+EPS_F);
    for (int j=0;j<S_D;j++) Adm[(size_t)b*900 + t*S_D+j] = ad[t*S_D+j]*inv;
  } else if (t < S_D + C_D) {
    int c = t - S_D;
    float s = 0; for (int j=0;j<S_D;j++) s += ac[j*C_D+c];
    float inv = 1.f/(s+EPS_F);
    for (int j=0;j<S_D;j++) Acc[(size_t)b*480 + j*C_D+c] = ac[j*C_D+c]*inv;
    s = 0; for (int j=0;j<S_D;j++) s += al[j*C_D+c];
    inv = 1.f/(s+EPS_F);
    for (int j=0;j<S_D;j++) Alc[(size_t)b*480 + j*C_D+c] = al[j*C_D+c]*inv;
  }
}

// ------------------------------------------------------------------
// prep: bf16 transposed weight concats + folded biases.
// K-order is PERMUTED to match the packed aggregate layout:
// Wcat  [768n x 3840k]: k<768 -> W_s;  k=768+kk*4+seg -> W_r[seg][kk]
//                       (seg 0:cur 1:slot 2:last 3:dom)
// Wcat2 [768n x 2304k]: k<768 -> W_s;  k=768+kk*2+seg -> W_r[seg?2:0][kk]
// Wg    [768n x 1536k]: W_g^T (unpermuted)
// ------------------------------------------------------------------
__global__ __launch_bounds__(256) void prep_weights_k(
    const float* __restrict__ W_r, const float* __restrict__ b_r,
    const float* __restrict__ W_s, const float* __restrict__ b_s,
    const float* __restrict__ W_g,
    bf16* __restrict__ Wcat, bf16* __restrict__ Wg, bf16* __restrict__ Wcat2,
    float* __restrict__ bslot, float* __restrict__ bcls)
{
  int id = blockIdx.x*256 + threadIdx.x;
  const int n1 = 768*3840, n2 = 768*1536, n3 = 768*2304;
  if (id < n1) {
    int n = id / 3840, k = id % 3840;
    float w;
    if (k < 768) w = W_s[k*768 + n];
    else { int j = k - 768, kk = j >> 2, seg = j & 3;
           w = W_r[((size_t)seg*768 + kk)*768 + n]; }
    Wcat[id] = __float2bfloat16(w);
  } else if (id < n1 + n2) {
    int j = id - n1; int n = j / 1536, k = j % 1536;
    Wg[j] = __float2bfloat16(W_g[(size_t)k*768 + n]);
  } else if (id < n1 + n2 + n3) {
    int j = id - n1 - n2; int n = j / 2304, k = j % 2304;
    float w;
    if (k < 768) w = W_s[k*768 + n];
    else { int jj = k - 768, kk = jj >> 1, seg = jj & 1;
           w = W_r[((size_t)(seg ? 2 : 0)*768 + kk)*768 + n]; }
    Wcat2[j] = __float2bfloat16(w);
  } else if (id < n1 + n2 + n3 + 768) {
    int n = id - n1 - n2 - n3;
    bslot[n] = b_s[n] + b_r[n] + b_r[768+n] + b_r[2*768+n] + b_r[3*768+n];
    bcls[n]  = b_s[n] + b_r[n] + b_r[2*768+n];
  }
}

// ------------------------------------------------------------------
// layer-1 aggregation + init. grid (chunkB, 3), 256 threads; thread =
// one column h of a 256-wide slice. Writes Gin right halves (x, bf16),
// Zs packed [row][kk*4+seg] (one uint2 store per slot row), Zc packed
// [row][kk*2+seg] (one uint store per cls row).
// ------------------------------------------------------------------
__global__ __launch_bounds__(256) void agg1_k(
    const float* __restrict__ slots, const float* __restrict__ cls,
    const float* __restrict__ Acr, const float* __restrict__ Acc,
    const float* __restrict__ Asl, const float* __restrict__ Alr,
    const float* __restrict__ Alc, const float* __restrict__ Adm,
    bf16* __restrict__ Gin, bf16* __restrict__ Zs, bf16* __restrict__ Zc,
    int b0, int rsBase)
{
  int lb = blockIdx.x, b = b0 + lb;
  int h = blockIdx.y*256 + threadIdx.x;
  float xs[S_D], xc[C_D];
  #pragma unroll
  for (int s = 0; s < S_D; ++s) xs[s] = slots[((size_t)b*S_D + s)*768 + h];
  #pragma unroll
  for (int c = 0; c < C_D; ++c) xc[c] = cls[((size_t)b*C_D + c)*768 + h];

  bf16* Gs = Gin + ((size_t)lb*S_D)*1536 + 768 + h;
  #pragma unroll
  for (int s = 0; s < S_D; ++s) Gs[(size_t)s*1536] = __float2bfloat16(xs[s]);
  bf16* Gc = Gin + ((size_t)(rsBase + lb*C_D))*1536 + 768 + h;
  #pragma unroll
  for (int c = 0; c < C_D; ++c) Gc[(size_t)c*1536] = __float2bfloat16(xc[c]);

  const float* acr = Acr + (size_t)b*480;
  const float* acc_= Acc + (size_t)b*480;
  const float* alr = Alr + (size_t)b*480;
  const float* alc = Alc + (size_t)b*480;
  const float* asl = Asl + (size_t)b*900;
  const float* adm = Adm + (size_t)b*900;

  char* Zsr = (char*)(Zs + ((size_t)lb*S_D)*3072 + (size_t)h*4);
  for (int s = 0; s < S_D; ++s) {
    float a1 = 0, a2 = 0, a3 = 0, a4 = 0;
    #pragma unroll
    for (int c = 0; c < C_D; ++c) { a1 += acr[s*C_D + c]*xc[c]; a3 += alr[s*C_D + c]*xc[c]; }
    #pragma unroll
    for (int t = 0; t < S_D; ++t) { a2 += asl[s*S_D + t]*xs[t]; a4 += adm[s*S_D + t]*xs[t]; }
    union { bf16 hv[4]; uint2 u; } p;
    p.hv[0] = __float2bfloat16(a1);
    p.hv[1] = __float2bfloat16(a2);
    p.hv[2] = __float2bfloat16(a3);
    p.hv[3] = __float2bfloat16(a4);
    *(uint2*)(Zsr + (size_t)s*3072*2) = p.u;
  }
  char* Zcr = (char*)(Zc + ((size_t)lb*C_D)*1536 + (size_t)h*2);
  for (int c = 0; c < C_D; ++c) {
    float a1 = 0, a3 = 0;
    #pragma unroll
    for (int s = 0; s < S_D; ++s) { a1 += acc_[s*C_D + c]*xs[s]; a3 += alc[s*C_D + c]*xs[s]; }
    union { bf16 hv[2]; unsigned u; } p;
    p.hv[0] = __float2bfloat16(a1);
    p.hv[1] = __float2bfloat16(a3);
    *(unsigned*)(Zcr + (size_t)c*1536*2) = p.u;
  }
}

// ------------------------------------------------------------------
// layer-2 aggregation (cls rows only), from layer-1 state Xo (bf16).
// Same packing as agg1's Zc. grid (chunkB, 3), 256 threads.
// ------------------------------------------------------------------
__global__ __launch_bounds__(256) void agg2_k(
    const bf16* __restrict__ Xo,
    const float* __restrict__ Acc, const float* __restrict__ Alc,
    bf16* __restrict__ Gin, bf16* __restrict__ Zc, int b0, int rsBase)
{
  int lb = blockIdx.x, b = b0 + lb;
  int h = blockIdx.y*256 + threadIdx.x;
  float xs[S_D];
  #pragma unroll
  for (int s = 0; s < S_D; ++s)
    xs[s] = __bfloat162float(Xo[((size_t)(lb*S_D + s))*768 + h]);

  const float* acc_ = Acc + (size_t)b*480;
  const float* alc  = Alc + (size_t)b*480;
  const bf16* Xc = Xo + ((size_t)(rsBase + lb*C_D))*768 + h;
  bf16* Gc  = Gin + ((size_t)(rsBase + lb*C_D))*1536 + 768 + h;
  char* Zcr = (char*)(Zc + ((size_t)lb*C_D)*1536 + (size_t)h*2);
  for (int c = 0; c < C_D; ++c) {
    float a1 = 0, a3 = 0;
    #pragma unroll
    for (int s = 0; s < S_D; ++s) { a1 += acc_[s*C_D + c]*xs[s]; a3 += alc[s*C_D + c]*xs[s]; }
    union { bf16 hv[2]; unsigned u; } p;
    p.hv[0] = __float2bfloat16(a1);
    p.hv[1] = __float2bfloat16(a3);
    *(unsigned*)(Zcr + (size_t)c*1536*2) = p.u;
    Gc[(size_t)c*1536] = Xc[(size_t)c*768];
  }
}

// ------------------------------------------------------------------
// MFMA GEMM: C[M x 768] = A[M x K] @ Bt[768 x K]^T. 128x128 tile, BK=64.
// T2 both-sides XOR swizzle + T1 bijective XCD swizzle + 2-phase LDS
// double-buffer prefetch. A dual-source: [0,SK) from A0, [SK,K) from A1.
// EPI 0: proj -> G left half = bf16(v + bias[col])
// EPI 1: gate -> Xo bf16     = relu(u)*g + x*(1-g)
// EPI 2: gate -> out f32     (cls rows; skip c==0)
// ------------------------------------------------------------------
template<int K, int EPI, int LDA0, int LDA1, int SK>
__global__ __launch_bounds__(256) void gemm_k(
    const bf16* __restrict__ A0, const bf16* __restrict__ A1,
    const bf16* __restrict__ Bt, bf16* __restrict__ G,
    bf16* __restrict__ Xo, float* __restrict__ out,
    const float* __restrict__ bias, const float* __restrict__ bg, int b0)
{
  __shared__ __align__(16) bf16 As[2][128*64];
  __shared__ __align__(16) bf16 Bs[2][128*64];
  const int tid  = threadIdx.x;
  const int lane = tid & 63;
  const int wave = tid >> 6;
  const int wm = wave >> 1, wn = wave & 1;

  // T1: bijective XCD-chunked swizzle (m204)
  const int nwg = gridDim.x;
  const int q = nwg >> 3, r = nwg & 7;
  const int xcd = blockIdx.x & 7, idx = blockIdx.x >> 3;
  const int wg = (xcd < r ? xcd*(q+1) : r*(q+1) + (xcd-r)*q) + idx;
  const int bm = wg / 6, bn = wg % 6;

  // T2 write side: pre-swizzled global source slot, linear LDS dest.
  const int swz = (((tid & 7) ^ ((tid >> 3) & 7))) << 3;   // elements
  const bf16* Ag0 = A0 + (size_t)(bm*128 + (tid>>3))*LDA0 + swz;
  const bf16* Ag1 = A1 + (size_t)(bm*128 + (tid>>3))*LDA1 + swz;
  const bf16* Bg  = Bt + (size_t)(bn*128 + (tid>>3))*K    + swz;
  const int ldsw = (wave*8)*64;

  f32x4 acc[4][4] = {};
  const int NT = K/64;

  auto stage = [&](int buf, int kt) {
    #pragma unroll
    for (int p = 0; p < 4; ++p) {
      const bf16* asrc = (kt < SK) ? (Ag0 + (size_t)(p*32)*LDA0 + kt)
                                   : (Ag1 + (size_t)(p*32)*LDA1 + (kt - SK));
      __builtin_amdgcn_global_load_lds(
        (const __attribute__((address_space(1))) void*)asrc,
        (__attribute__((address_space(3))) void*)(&As[buf][ldsw + p*32*64]), 16, 0, 0);
      __builtin_amdgcn_global_load_lds(
        (const __attribute__((address_space(1))) void*)(Bg + (size_t)(p*32)*K + kt),
        (__attribute__((address_space(3))) void*)(&Bs[buf][ldsw + p*32*64]), 16, 0, 0);
    }
  };

  stage(0, 0);
  __syncthreads();
  int cur = 0;
  #pragma unroll 1
  for (int t = 0; t < NT; ++t) {
    if (t + 1 < NT) stage(cur ^ 1, (t + 1)*64);   // prefetch flies under MFMA
    const bf16* Asb = As[cur];
    const bf16* Bsb = Bs[cur];
    #pragma unroll
    for (int ks = 0; ks < 64; ks += 32) {
      bf16x8 af[4], bfv[4];
      const int sa = ((((ks >> 3) + (lane >> 4)) ^ (lane & 7))) << 3;
      #pragma unroll
      for (int i = 0; i < 4; ++i) {
        int m = wm*64 + i*16 + (lane & 15);
        af[i]  = *(const bf16x8*)&Asb[m*64 + sa];
        int n = wn*64 + i*16 + (lane & 15);
        bfv[i] = *(const bf16x8*)&Bsb[n*64 + sa];
      }
      #pragma unroll
      for (int i = 0; i < 4; ++i)
        #pragma unroll
        for (int j = 0; j < 4; ++j)
          acc[i][j] = __builtin_amdgcn_mfma_f32_16x16x32_bf16(af[i], bfv[j], acc[i][j], 0, 0, 0);
    }
    __syncthreads();   // vmcnt(0)+barrier after compute: prefetch has landed
    cur ^= 1;
  }

  const int rbase = bm*128 + wm*64 + ((lane>>4)<<2);
  const int cbase = bn*128 + wn*64 + (lane & 15);
  #pragma unroll
  for (int i = 0; i < 4; ++i) {
    #pragma unroll
    for (int j = 0; j < 4; ++j) {
      const int col = cbase + j*16;
      #pragma unroll
      for (int r2 = 0; r2 < 4; ++r2) {
        const int row = rbase + i*16 + r2;
        float v = acc[i][j][r2];
        if constexpr (EPI == 0) {
          G[(size_t)row*1536 + col] = __float2bfloat16(v + bias[col]);
        } else if constexpr (EPI == 1) {
          v += bg[col];
          float g = 1.f/(1.f + __expf(-v));
          float u = __bfloat162float(G[(size_t)row*1536 + col]);
          float x = __bfloat162float(G[(size_t)row*1536 + 768 + col]);
          Xo[(size_t)row*H_D + col] = __float2bfloat16(fmaxf(u, 0.f)*g + x*(1.f - g));
        } else { // EPI == 2: final cls gate -> out
          v += bg[col];
          float g = 1.f/(1.f + __expf(-v));
          float u = __bfloat162float(G[(size_t)row*1536 + col]);
          int bb = row >> 4, c = row & 15;
          if (c >= 1) {
            float x = __bfloat162float(Xo[(size_t)row*H_D + col]);
            out[((size_t)(b0 + bb)*15 + (c - 1))*H_D + col] =
                fmaxf(u, 0.f)*g + x*(1.f - g);
          }
        }
      }
    }
  }
}

// ------------------------------------------------------------------
extern "C" void kernel_launch(void* const* d_in, const int* in_sizes, int n_in,
                              void* d_out, int out_size, void* d_ws, size_t ws_size,
                              hipStream_t stream)
{
  const float* slots  = (const float*)d_in[0];
  const float* cls    = (const float*)d_in[1];
  const float* a_cur  = (const float*)d_in[2];
  const float* a_slot = (const float*)d_in[3];
  const float* a_last = (const float*)d_in[4];
  const float* a_dom  = (const float*)d_in[5];
  const float* W_r    = (const float*)d_in[6];
  const float* b_r    = (const float*)d_in[7];
  const float* W_s    = (const float*)d_in[8];
  const float* b_s    = (const float*)d_in[9];
  const float* W_g    = (const float*)d_in[10];
  const float* b_g    = (const float*)d_in[11];
  float* out = (float*)d_out;

  char* base = (char*)d_ws;
  size_t off = 0;
  auto alloc = [&](size_t bytes) -> void* {
    void* r = base + off;
    off = (off + bytes + 255) & ~(size_t)255;
    return r;
  };

  float* Acr = (float*)alloc((size_t)512*480*4);
  float* Acc = (float*)alloc((size_t)512*480*4);
  float* Alr = (float*)alloc((size_t)512*480*4);
  float* Alc = (float*)alloc((size_t)512*480*4);
  float* Asl = (float*)alloc((size_t)512*900*4);
  float* Adm = (float*)alloc((size_t)512*900*4);
  bf16* Wcat   = (bf16*)alloc((size_t)768*3840*2);
  bf16* Wg     = (bf16*)alloc((size_t)768*1536*2);
  bf16* Wcat2  = (bf16*)alloc((size_t)768*2304*2);
  float* bslot = (float*)alloc(768*4);
  float* bcls  = (float*)alloc(768*4);
  size_t fixedOff = off;

  // per-batch: Gin [46x1536] + Xo [46x768] + Zs [30x3072] + Zc [16x1536], all bf16
  const size_t perBatch = (size_t)46*1536*2 + (size_t)46*768*2
                        + (size_t)30*3072*2 + (size_t)16*1536*2;
  int chunkB = 512;
  while (chunkB > 64 && fixedOff + perBatch*(size_t)chunkB + 65536 > ws_size) chunkB >>= 1;

  const int rows_s = chunkB * S_D;       // slot rows
  const int rows_c = chunkB * C_D;       // cls rows
  const int rows_a = chunkB * (S_D + C_D);
  bf16* Gin = (bf16*)alloc((size_t)rows_a*1536*2);
  bf16* Xo  = (bf16*)alloc((size_t)rows_a*768*2);
  bf16* Zs  = (bf16*)alloc((size_t)rows_s*3072*2);
  bf16* Zc  = (bf16*)alloc((size_t)rows_c*1536*2);
  bf16* GinC = Gin + (size_t)rows_s*1536;
  bf16* XoC  = Xo  + (size_t)rows_s*768;

  prep_norm_k<<<512, 64, 0, stream>>>(a_cur, a_slot, a_last, a_dom,
                                      Acr, Acc, Asl, Alr, Alc, Adm);
  {
    int tot = 768*3840 + 768*1536 + 768*2304 + 768;
    prep_weights_k<<<(tot+255)/256, 256, 0, stream>>>(W_r, b_r, W_s, b_s, W_g,
                                                      Wcat, Wg, Wcat2, bslot, bcls);
  }

  for (int b0 = 0; b0 < 512; b0 += chunkB) {
    // ---- layer 1 ----
    agg1_k<<<dim3(chunkB, 3), 256, 0, stream>>>(slots, cls, Acr, Acc, Asl, Alr,
                                                Alc, Adm, Gin, Zs, Zc, b0, rows_s);
    // slot proj: A = [x | Zs packed], K=3840 -> Gin_s left (u + bslot)
    gemm_k<3840, 0, 1536, 3072, 768><<<(rows_s/128)*6, 256, 0, stream>>>(
        Gin + 768, Zs, Wcat, Gin, Xo, out, bslot, b_g, b0);
    // cls proj: A = [x | Zc packed], K=2304 -> Gin_c left (u + bcls)
    gemm_k<2304, 0, 1536, 1536, 768><<<(rows_c/128)*6, 256, 0, stream>>>(
        GinC + 768, Zc, Wcat2, GinC, XoC, out, bcls, b_g, b0);
    // gate (all rows): A = Gin = [u | x], K=1536 -> Xo bf16
    gemm_k<1536, 1, 1536, 1536, 1536><<<(rows_a/128)*6, 256, 0, stream>>>(
        Gin, Gin, Wg, Gin, Xo, out, bslot, b_g, b0);
    // ---- layer 2 (cls rows only) ----
    agg2_k<<<dim3(chunkB, 3), 256, 0, stream>>>(Xo, Acc, Alc, Gin, Zc, b0, rows_s);
    gemm_k<2304, 0, 1536, 1536, 768><<<(rows_c/128)*6, 256, 0, stream>>>(
        GinC + 768, Zc, Wcat2, GinC, XoC, out, bcls, b_g, b0);
    // final gate -> out
    gemm_k<1536, 2, 1536, 1536, 1536><<<(rows_c/128)*6, 256, 0, stream>>>(
        GinC, GinC, Wg, GinC, XoC, out, bcls, b_g, b0);
  }
}